// Round 3
// baseline (1665.260 us; speedup 1.0000x reference)
//
#include <hip/hip_runtime.h>
#include <hip/hip_bf16.h>
#include <math.h>

#define V 32000
#define B 32
#define E 64
#define H 256
#define T 128
#define NROW (B*T)     // 4096 rows, row = t*B + b
#define NC 128         // vocab cols per block (logits)
#define NVB (V/NC)     // 250
#define MR 128         // rows per block (logits)
#define RBLK 4         // recurrence blocks (barrier group)

typedef __attribute__((ext_vector_type(8))) short bf16x8;
typedef __attribute__((ext_vector_type(4))) float f32x4;
typedef __attribute__((ext_vector_type(8))) unsigned short u16x8;

// ws layout (float offsets)
#define OFF_XS   0
#define OFF_XW   (OFF_XS + NROW*E)          // 262144  (xw 16MB; region reused for WoT after recur)
#define OFF_HB   (OFF_XW + NROW*4*H)        // 4456448 (h bf16: NROW*H ushort = 2MB)
#define OFF_PM   (OFF_HB + NROW*H/2)        // 4980736
#define OFF_PS   (OFF_PM + NVB*NROW)        // 6004736
#define OFF_TL   (OFF_PS + NVB*NROW)        // 7028736 (+4096)
#define OFF_UT   (OFF_TL + NROW)            // 7032832 (UT bf16: 1024*256 ushort = 512KB)
#define OFF_BAR  (OFF_UT + 4*H*H/2)         // 7163904 (+16)  total ~28.7 MB

static __device__ __forceinline__ unsigned short f2bf(float f) {
    union { float f; unsigned int u; } x; x.f = f;
    unsigned int r = x.u + 0x7fffu + ((x.u >> 16) & 1u);   // RNE
    return (unsigned short)(r >> 16);
}
static __device__ __forceinline__ float sigmoidf_(float x) { return 1.f / (1.f + __expf(-x)); }
static __device__ __forceinline__ float tanhf_(float x)    { return 2.f / (1.f + __expf(-2.f * x)) - 1.f; }

// ---------------- kernel 1: embedding gather (teacher forcing) ----------------
__global__ void lstm_embed(const int* __restrict__ x, const float* __restrict__ emb,
                           const int* __restrict__ start, float* __restrict__ xs,
                           float* __restrict__ out, unsigned int* __restrict__ bar) {
    int idx = blockIdx.x * 256 + threadIdx.x;
    if (idx == 0) { out[0] = 0.f; bar[0] = 0u; }   // zero accumulator + barrier each launch
    if (idx >= T * B * E) return;
    int t   = idx / (B * E);
    int rem = idx - t * (B * E);
    int b   = rem >> 6;
    int e   = rem & 63;
    int tok = (t == 0) ? start[0] : x[b * T + (t - 1)];
    xs[idx] = emb[tok * E + e];
}

// ------- kernel 2: XW[row][j*4+g] = xs @ W_g + bias_g (gate-interleaved) -------
__global__ void lstm_xw(const float* __restrict__ xs, float* __restrict__ xw,
                        const float* __restrict__ Wi, const float* __restrict__ Wf,
                        const float* __restrict__ Wog, const float* __restrict__ Wc,
                        const float* __restrict__ bi, const float* __restrict__ bf,
                        const float* __restrict__ bog, const float* __restrict__ bc) {
    int idx = blockIdx.x * 256 + threadIdx.x;   // NROW*H threads
    int row = idx >> 8, j = idx & 255;
    float a0 = bi[j], a1 = bf[j], a2 = bog[j], a3 = bc[j];
    const float* xr = xs + row * E;
    #pragma unroll 8
    for (int e = 0; e < E; ++e) {
        float xe = xr[e];
        a0 += xe * Wi [e * H + j];
        a1 += xe * Wf [e * H + j];
        a2 += xe * Wog[e * H + j];
        a3 += xe * Wc [e * H + j];
    }
    f32x4 v; v[0] = a0; v[1] = a1; v[2] = a2; v[3] = a3;
    *(f32x4*)&xw[(size_t)row * 1024 + j * 4] = v;
}

// ------ kernel 3: U_g[256][256] fp32 -> UT[(j*4+g)][k] bf16 (transposed) -------
__global__ __launch_bounds__(256) void lstm_ut(
        const float* __restrict__ Ui, const float* __restrict__ Uf,
        const float* __restrict__ Uog, const float* __restrict__ Uc,
        unsigned short* __restrict__ UT) {
    __shared__ unsigned short tle[64][65];
    const int g = blockIdx.z;
    const float* U = (g == 0) ? Ui : (g == 1) ? Uf : (g == 2) ? Uog : Uc;
    const int j0 = blockIdx.x * 64, k0 = blockIdx.y * 64;
    const int tid = threadIdx.x;
    for (int i = tid; i < 64 * 64; i += 256) {
        int kk = i >> 6, jj = i & 63;
        tle[kk][jj] = f2bf(U[(size_t)(k0 + kk) * H + j0 + jj]);
    }
    __syncthreads();
    for (int c = tid; c < 512; c += 256) {
        int jj = c >> 3, kc = c & 7;
        u16x8 v;
        #pragma unroll
        for (int e = 0; e < 8; ++e) v[e] = tle[kc * 8 + e][jj];
        *(u16x8*)(UT + ((size_t)(j0 + jj) * 4 + g) * H + k0 + kc * 8) = v;
    }
}

// ---- kernel 4: recurrence, 4 persistent blocks, U in VGPRs, atomic barrier ---
__global__ __launch_bounds__(512) void lstm_recur_mfma(
        const float* __restrict__ xw, const unsigned short* __restrict__ UT,
        unsigned short* __restrict__ hb, unsigned int* __restrict__ bar) {
    __shared__ float gl[32][264];               // gates [batch][col_local], pad 8
    const int tid  = threadIdx.x;
    const int blk  = blockIdx.x;
    const int lane = tid & 63, w = tid >> 6;    // 8 waves
    const int lr = lane & 15, lg = lane >> 4;

    // persistent A-frags: this block's 256 U^T cols, in registers forever
    bf16x8 A[2][8];
    #pragma unroll
    for (int ci = 0; ci < 2; ++ci)
        #pragma unroll
        for (int kt = 0; kt < 8; ++kt) {
            int col = blk * 256 + (w * 2 + ci) * 16 + lr;
            A[ci][kt] = *(const bf16x8*)(UT + (size_t)col * H + kt * 32 + lg * 8);
        }

    const int cb_b  = tid >> 4;                 // combine: batch 0..31
    const int cb_jq = tid & 15;                 //          j-quad 0..15
    float c_reg[4] = {0.f, 0.f, 0.f, 0.f};

    for (int t = 0; t < T; ++t) {
        if (t > 0) {
            bf16x8 Bv[2][8];
            #pragma unroll
            for (int nt = 0; nt < 2; ++nt)
                #pragma unroll
                for (int kt = 0; kt < 8; ++kt) {
                    int row = (t - 1) * B + nt * 16 + lr;
                    Bv[nt][kt] = *(const bf16x8*)(hb + (size_t)row * H + kt * 32 + lg * 8);
                }
            f32x4 acc[2][2] = {};
            #pragma unroll
            for (int kt = 0; kt < 8; ++kt)
                #pragma unroll
                for (int ci = 0; ci < 2; ++ci)
                    #pragma unroll
                    for (int nt = 0; nt < 2; ++nt)
                        acc[ci][nt] = __builtin_amdgcn_mfma_f32_16x16x32_bf16(
                            A[ci][kt], Bv[nt][kt], acc[ci][nt], 0, 0, 0);
            #pragma unroll
            for (int ci = 0; ci < 2; ++ci)
                #pragma unroll
                for (int nt = 0; nt < 2; ++nt)
                    #pragma unroll
                    for (int r = 0; r < 4; ++r)
                        gl[nt * 16 + lr][(w * 2 + ci) * 16 + lg * 4 + r] = acc[ci][nt][r];
        }
        __syncthreads();

        // combine: thread owns (batch cb_b, 4 consecutive j), c in registers
        const float* xwr = xw + (size_t)(t * B + cb_b) * 1024 + blk * 256 + cb_jq * 16;
        ushort4 hout;
        unsigned short* hvec = (unsigned short*)&hout;
        #pragma unroll
        for (int jj = 0; jj < 4; ++jj) {
            f32x4 g4 = *(const f32x4*)&xwr[jj * 4];
            if (t > 0) {
                f32x4 u4 = *(const f32x4*)&gl[cb_b][cb_jq * 16 + jj * 4];
                g4 = g4 + u4;
            }
            float iv = sigmoidf_(g4[0]);
            float fv = sigmoidf_(g4[1]);
            float ov = sigmoidf_(g4[2]);
            float cb = tanhf_(g4[3]);
            float c  = fv * c_reg[jj] + iv * cb;
            c_reg[jj] = c;
            hvec[jj] = f2bf(ov * tanhf_(c));
        }
        *(ushort4*)(hb + (size_t)(t * B + cb_b) * H + blk * 64 + cb_jq * 4) = hout;

        if (t < T - 1) {
            __syncthreads();                    // all stores issued & vmcnt drained
            __threadfence();                    // release: flush to device scope
            if (tid == 0) {
                __hip_atomic_fetch_add(bar, 1u, __ATOMIC_RELEASE, __HIP_MEMORY_SCOPE_AGENT);
                const unsigned int tgt = (unsigned int)(RBLK * (t + 1));
                while (__hip_atomic_load(bar, __ATOMIC_RELAXED, __HIP_MEMORY_SCOPE_AGENT) < tgt)
                    __builtin_amdgcn_s_sleep(1);
            }
            __syncthreads();
            __threadfence();                    // acquire: invalidate before reading others' h
        }
    }
}

// -------- kernel 5: Wo [K=256][V] fp32  ->  WoT [V][K=256] bf16 (transpose) ---
__global__ __launch_bounds__(256) void lstm_wot(const float* __restrict__ Wo,
                                                unsigned short* __restrict__ WoT) {
    __shared__ unsigned short tle[64][65];
    const int n0 = blockIdx.x * 64, k0 = blockIdx.y * 64;
    const int tid = threadIdx.x;
    for (int i = tid; i < 64 * 64; i += 256) {
        int kk = i >> 6, nn = i & 63;
        tle[kk][nn] = f2bf(Wo[(size_t)(k0 + kk) * V + n0 + nn]);
    }
    __syncthreads();
    for (int c = tid; c < 512; c += 256) {
        int nn = c >> 3, kc = c & 7;
        u16x8 v;
        #pragma unroll
        for (int e = 0; e < 8; ++e) v[e] = tle[kc * 8 + e][nn];
        *(u16x8*)(WoT + (size_t)(n0 + nn) * H + k0 + kc * 8) = v;
    }
}

// ------ kernel 6: bf16 MFMA logits GEMM + fused per-(row,vchunk) partials -----
__global__ __launch_bounds__(512) void lstm_logits_mfma(
        const unsigned short* __restrict__ hb, const unsigned short* __restrict__ WoT,
        const float* __restrict__ bo, const int* __restrict__ x,
        float* __restrict__ pm, float* __restrict__ ps, float* __restrict__ tl) {
    __shared__ union {
        unsigned short ab[2][MR * H];   // [0]=A tile 64KB, [1]=B tile 64KB
        float lg[MR * 132];             // logits buffer, used after MFMA
    } sm;
    const int tid = threadIdx.x;
    const int vb  = blockIdx.x * NC;
    const int r0  = blockIdx.y * MR;

    const uint4* srcA = (const uint4*)(hb  + (size_t)r0 * H);
    const uint4* srcB = (const uint4*)(WoT + (size_t)vb * H);
    for (int c = tid; c < MR * H / 8; c += 512) {
        int row = c >> 5, c16 = c & 31;
        uint4 va = srcA[c];
        *(uint4*)((char*)sm.ab[0] + row * 512 + ((c16 ^ (row & 7)) << 4)) = va;
        uint4 vbv = srcB[c];
        *(uint4*)((char*)sm.ab[1] + row * 512 + ((c16 ^ (row & 7)) << 4)) = vbv;
    }
    __syncthreads();

    const int lane = tid & 63, wid = tid >> 6;
    const int wr = wid >> 2, wc = wid & 3;
    const int lr = lane & 15, lg = lane >> 4;
    const int swz = lr & 7;
    f32x4 acc[4][2] = {};
    const char* aBase = (const char*)sm.ab[0] + (wr * 64 + lr) * 512;
    const char* bBase = (const char*)sm.ab[1] + (wc * 32 + lr) * 512;
    #pragma unroll
    for (int ks = 0; ks < 8; ++ks) {
        bf16x8 a[4], bfr[2];
        #pragma unroll
        for (int mf = 0; mf < 4; ++mf)
            a[mf] = *(const bf16x8*)(aBase + mf * 16 * 512 + (((ks * 4 + lg) ^ swz) << 4));
        #pragma unroll
        for (int nf = 0; nf < 2; ++nf)
            bfr[nf] = *(const bf16x8*)(bBase + nf * 16 * 512 + (((ks * 4 + lg) ^ swz) << 4));
        #pragma unroll
        for (int mf = 0; mf < 4; ++mf)
            #pragma unroll
            for (int nf = 0; nf < 2; ++nf)
                acc[mf][nf] = __builtin_amdgcn_mfma_f32_16x16x32_bf16(a[mf], bfr[nf], acc[mf][nf], 0, 0, 0);
    }
    __syncthreads();

    float bocol[2];
    #pragma unroll
    for (int nf = 0; nf < 2; ++nf) bocol[nf] = bo[vb + wc * 32 + nf * 16 + lr];
    #pragma unroll
    for (int mf = 0; mf < 4; ++mf)
        #pragma unroll
        for (int nf = 0; nf < 2; ++nf)
            #pragma unroll
            for (int r = 0; r < 4; ++r) {
                int row = wr * 64 + mf * 16 + lg * 4 + r;
                int col = wc * 32 + nf * 16 + lr;
                sm.lg[row * 132 + col] = acc[mf][nf][r] + bocol[nf];
            }
    __syncthreads();

    {
        const int row = tid >> 2, q = tid & 3;
        const float* lp = &sm.lg[row * 132 + q * 32];
        float m = -1e30f;
        #pragma unroll
        for (int i = 0; i < 32; ++i) m = fmaxf(m, lp[i]);
        m = fmaxf(m, __shfl_xor(m, 1));
        m = fmaxf(m, __shfl_xor(m, 2));
        float s = 0.f;
        #pragma unroll
        for (int i = 0; i < 32; ++i) s += expf(lp[i] - m);
        s += __shfl_xor(s, 1);
        s += __shfl_xor(s, 2);
        if (q == 0) {
            const int gr = r0 + row;
            pm[(size_t)blockIdx.x * NROW + gr] = m;
            ps[(size_t)blockIdx.x * NROW + gr] = s;
            const int tt = gr >> 5, bb = gr & 31;
            const int tgt = x[bb * T + tt];
            if (tgt >= vb && tgt < vb + NC)
                tl[gr] = sm.lg[row * 132 + (tgt - vb)];
        }
    }
}

// ---------------- kernel 7: combine partials, reduce NLL ----------------------
__global__ __launch_bounds__(256) void lstm_lse(
        const float* __restrict__ pm, const float* __restrict__ ps,
        const float* __restrict__ tl, float* __restrict__ out) {
    const int row = blockIdx.x * 256 + threadIdx.x;
    float m = -1e30f, s = 0.f;
    for (int c = 0; c < NVB; ++c) {
        float mc = pm[(size_t)c * NROW + row];
        float sc = ps[(size_t)c * NROW + row];
        if (mc > m) { s = s * expf(m - mc) + sc; m = mc; }
        else        { s += sc * expf(mc - m); }
    }
    float nll = (m + logf(s)) - tl[row];
    __shared__ float red[256];
    red[threadIdx.x] = nll;
    __syncthreads();
    for (int off = 128; off > 0; off >>= 1) {
        if (threadIdx.x < off) red[threadIdx.x] += red[threadIdx.x + off];
        __syncthreads();
    }
    if (threadIdx.x == 0) atomicAdd(out, red[0]);
}

extern "C" void kernel_launch(void* const* d_in, const int* in_sizes, int n_in,
                              void* d_out, int out_size, void* d_ws, size_t ws_size,
                              hipStream_t stream) {
    const int*   x     = (const int*)d_in[0];
    const float* emb   = (const float*)d_in[1];
    const float* Wi    = (const float*)d_in[2];
    const float* Ui    = (const float*)d_in[3];
    const float* bi    = (const float*)d_in[4];
    const float* Wf    = (const float*)d_in[5];
    const float* Uf    = (const float*)d_in[6];
    const float* bf    = (const float*)d_in[7];
    const float* Wog   = (const float*)d_in[8];
    const float* Uog   = (const float*)d_in[9];
    const float* bog   = (const float*)d_in[10];
    const float* Wc    = (const float*)d_in[11];
    const float* Uc    = (const float*)d_in[12];
    const float* bc    = (const float*)d_in[13];
    const float* Wo    = (const float*)d_in[14];
    const float* bo    = (const float*)d_in[15];
    const int*   start = (const int*)d_in[16];
    float* ws  = (float*)d_ws;
    float* out = (float*)d_out;

    float*          xs  = ws + OFF_XS;
    float*          xw  = ws + OFF_XW;
    unsigned short* WoT = (unsigned short*)(ws + OFF_XW);   // aliases xw (dead after recur)
    unsigned short* hbf = (unsigned short*)(ws + OFF_HB);
    float*          pm  = ws + OFF_PM;
    float*          psB = ws + OFF_PS;
    float*          tlB = ws + OFF_TL;
    unsigned short* UT  = (unsigned short*)(ws + OFF_UT);
    unsigned int*   bar = (unsigned int*)(ws + OFF_BAR);

    lstm_embed <<<(T * B * E + 255) / 256, 256, 0, stream>>>(x, emb, start, xs, out, bar);
    lstm_xw    <<<(NROW * H) / 256,        256, 0, stream>>>(xs, xw, Wi, Wf, Wog, Wc, bi, bf, bog, bc);
    lstm_ut    <<<dim3(H / 64, H / 64, 4), 256, 0, stream>>>(Ui, Uf, Uog, Uc, UT);
    lstm_recur_mfma<<<RBLK, 512, 0, stream>>>(xw, UT, hbf, bar);
    lstm_wot   <<<dim3(V / 64, H / 64), 256, 0, stream>>>(Wo, WoT);
    lstm_logits_mfma<<<dim3(NVB, NROW / MR), 512, 0, stream>>>(hbf, WoT, bo, x, pm, psB, tlB);
    lstm_lse   <<<NROW / 256, 256, 0, stream>>>(pm, psB, tlB, out);
}